// Round 6
// baseline (1177.356 us; speedup 1.0000x reference)
//
#include <hip/hip_runtime.h>
#include <hip/hip_bf16.h>

#define NN 50000
#define NE 800000
#define DH 128
#define DE 16
#define DM 128
#define K1 273
#define K1P 288
#define EPB 32
#define NPB 32
#define M1S 136   // padded LDS row stride for m1/m2/t tiles (272B, 16B-aligned)

typedef __attribute__((ext_vector_type(8))) short s16x8;
typedef __attribute__((ext_vector_type(4))) short s16x4;
typedef __attribute__((ext_vector_type(4))) float f32x4;

// Device-global scratch: no dependence on ws_size. Rewritten every launch.
__device__ float g_msum[NN * DM];                    // 25.6 MB fp32 accumulator
__device__ __hip_bfloat16 g_W1p[128 * K1P];          // padded/permuted We1, bf16
__device__ __hip_bfloat16 g_W2b[128 * 128];
__device__ __hip_bfloat16 g_Wh1b[128 * 256];
__device__ __hip_bfloat16 g_Wh2b[128 * 128];

__device__ __forceinline__ float bf2f(__hip_bfloat16 v) { return __bfloat162float(v); }
__device__ __forceinline__ __hip_bfloat16 f2bf(float v) { return __float2bfloat16(v); }
__device__ __forceinline__ short bfbits(float f) {
    __hip_bfloat16 b = __float2bfloat16(f);
    return *reinterpret_cast<short*>(&b);
}
__device__ __forceinline__ float silu(float v) { return v / (1.f + __expf(-v)); }

__global__ __launch_bounds__(256) void zero_msum() {
    int i = blockIdx.x * 256 + threadIdx.x;     // grid 6250
    float4* p = (float4*)g_msum;
    if (i < NN * DM / 4) p[i] = make_float4(0.f, 0.f, 0.f, 0.f);
}

// Convert all four weight matrices fp32->bf16; We1 additionally permuted/padded:
// e_in col order [h_row h_col (0:256) | ea (256:272) | radial (272) | 0-pad to 288]
__global__ __launch_bounds__(256) void prep_weights(
    const float* __restrict__ We1, const float* __restrict__ We2,
    const float* __restrict__ Wh1, const float* __restrict__ Wh2) {
    int i = blockIdx.x * 256 + threadIdx.x;
    if (i < 128 * K1P) {                 // 36864
        int n = i / K1P, k = i % K1P;
        int src;
        if (k < 256) src = k;            // h_row, h_col
        else if (k < 272) src = k + 1;   // edge_attr (We1 cols 257..272)
        else if (k == 272) src = 256;    // radial (We1 col 256)
        else src = -1;                   // zero pad
        g_W1p[i] = (src >= 0) ? f2bf(We1[n * K1 + src]) : f2bf(0.f);
    }
    if (i < 128 * 128) g_W2b[i]  = f2bf(We2[i]);
    if (i < 128 * 256) g_Wh1b[i] = f2bf(Wh1[i]);
    if (i < 128 * 128) g_Wh2b[i] = f2bf(Wh2[i]);
}

__global__ __launch_bounds__(256) void edge_kernel(
    const float* __restrict__ x,
    const float* __restrict__ h,
    const float* __restrict__ ea,
    const float* __restrict__ be1,
    const float* __restrict__ be2,
    const float* __restrict__ Wa,             // [128]
    const float* __restrict__ ba,             // [1]
    const int* __restrict__ eidx)             // [2][NE] int32 planar
{
    __shared__ __align__(16) __hip_bfloat16 s_ein[EPB * K1P];
    __shared__ __align__(16) __hip_bfloat16 s_m1[EPB * M1S];
    __shared__ __align__(16) __hip_bfloat16 s_m2[EPB * M1S];
    __shared__ float s_part[8 * EPB];
    __shared__ float s_att[EPB];
    __shared__ int s_row[EPB];
    __shared__ int s_col[EPB];

    const int tid  = threadIdx.x;
    const int lane = tid & 63;
    const int wave = tid >> 6;
    const int e0   = blockIdx.x * EPB;

    if (tid < EPB) {
        int e = e0 + tid;
        int r = eidx[e];
        int c = eidx[NE + e];
        s_row[tid] = r;
        s_col[tid] = c;
        float dx = x[r * 3 + 0] - x[c * 3 + 0];
        float dy = x[r * 3 + 1] - x[c * 3 + 1];
        float dz = x[r * 3 + 2] - x[c * 3 + 2];
        float rad = sqrtf(dx * dx + dy * dy + dz * dz);
        s_ein[tid * K1P + 272] = f2bf(rad);
        #pragma unroll
        for (int k = 273; k < 288; k++) s_ein[tid * K1P + k] = f2bf(0.f);
    }
    __syncthreads();

    // gather h rows (fp32 -> bf16): e_in[e][0:128]=h[row], [128:256]=h[col]
    for (int i = tid; i < 64 * 16; i += 256) {
        int r = i >> 4, u = i & 15;
        int node = (r & 32) ? s_col[r & 31] : s_row[r & 31];
        const float* hp = h + (size_t)node * DH + u * 8;
        float4 v0 = *(const float4*)(hp);
        float4 v1 = *(const float4*)(hp + 4);
        s16x8 t;
        t[0] = bfbits(v0.x); t[1] = bfbits(v0.y); t[2] = bfbits(v0.z); t[3] = bfbits(v0.w);
        t[4] = bfbits(v1.x); t[5] = bfbits(v1.y); t[6] = bfbits(v1.z); t[7] = bfbits(v1.w);
        *(s16x8*)(s_ein + (r & 31) * K1P + ((r & 32) ? DH : 0) + u * 8) = t;
    }
    // edge_attr (fp32 -> bf16) -> e_in[e][256:272]
    if (tid < 64) {
        int e = tid >> 1, u = tid & 1;
        const float* ep = ea + (size_t)(e0 + e) * DE + u * 8;
        float4 v0 = *(const float4*)(ep);
        float4 v1 = *(const float4*)(ep + 4);
        s16x8 t;
        t[0] = bfbits(v0.x); t[1] = bfbits(v0.y); t[2] = bfbits(v0.z); t[3] = bfbits(v0.w);
        t[4] = bfbits(v1.x); t[5] = bfbits(v1.y); t[6] = bfbits(v1.z); t[7] = bfbits(v1.w);
        *(s16x8*)(s_ein + e * K1P + 256 + u * 8) = t;
    }
    __syncthreads();

    const int l15 = lane & 15;
    const int kq  = (lane >> 4) * 8;
    const int rq  = (lane >> 4) * 4;
    const int nb  = wave * 32;

    // layer 1: m1 = silu(e_in @ We1^T + be1), K=288
    {
        float bias0 = be1[nb + l15];
        float bias1 = be1[nb + 16 + l15];
        f32x4 acc00 = {bias0, bias0, bias0, bias0};
        f32x4 acc01 = {bias1, bias1, bias1, bias1};
        f32x4 acc10 = acc00, acc11 = acc01;
        const __hip_bfloat16* a0p = s_ein + l15 * K1P + kq;
        const __hip_bfloat16* a1p = s_ein + (16 + l15) * K1P + kq;
        const __hip_bfloat16* b0p = g_W1p + (size_t)(nb + l15) * K1P + kq;
        const __hip_bfloat16* b1p = g_W1p + (size_t)(nb + 16 + l15) * K1P + kq;
        #pragma unroll
        for (int k0 = 0; k0 < K1P; k0 += 32) {
            s16x8 a0 = *(const s16x8*)(a0p + k0);
            s16x8 a1 = *(const s16x8*)(a1p + k0);
            s16x8 b0 = *(const s16x8*)(b0p + k0);
            s16x8 b1 = *(const s16x8*)(b1p + k0);
            acc00 = __builtin_amdgcn_mfma_f32_16x16x32_bf16(a0, b0, acc00, 0, 0, 0);
            acc01 = __builtin_amdgcn_mfma_f32_16x16x32_bf16(a0, b1, acc01, 0, 0, 0);
            acc10 = __builtin_amdgcn_mfma_f32_16x16x32_bf16(a1, b0, acc10, 0, 0, 0);
            acc11 = __builtin_amdgcn_mfma_f32_16x16x32_bf16(a1, b1, acc11, 0, 0, 0);
        }
        #pragma unroll
        for (int r = 0; r < 4; r++) {
            s_m1[(rq + r) * M1S + nb + l15]           = f2bf(silu(acc00[r]));
            s_m1[(rq + r) * M1S + nb + 16 + l15]      = f2bf(silu(acc01[r]));
            s_m1[(16 + rq + r) * M1S + nb + l15]      = f2bf(silu(acc10[r]));
            s_m1[(16 + rq + r) * M1S + nb + 16 + l15] = f2bf(silu(acc11[r]));
        }
    }
    __syncthreads();

    // layer 2: m2 = silu(m1 @ We2^T + be2), K=128
    {
        float bias0 = be2[nb + l15];
        float bias1 = be2[nb + 16 + l15];
        f32x4 acc00 = {bias0, bias0, bias0, bias0};
        f32x4 acc01 = {bias1, bias1, bias1, bias1};
        f32x4 acc10 = acc00, acc11 = acc01;
        #pragma unroll
        for (int k0 = 0; k0 < 128; k0 += 32) {
            s16x8 a0 = *(const s16x8*)(s_m1 + l15 * M1S + k0 + kq);
            s16x8 a1 = *(const s16x8*)(s_m1 + (16 + l15) * M1S + k0 + kq);
            s16x8 b0 = *(const s16x8*)(g_W2b + (size_t)(nb + l15) * 128 + k0 + kq);
            s16x8 b1 = *(const s16x8*)(g_W2b + (size_t)(nb + 16 + l15) * 128 + k0 + kq);
            acc00 = __builtin_amdgcn_mfma_f32_16x16x32_bf16(a0, b0, acc00, 0, 0, 0);
            acc01 = __builtin_amdgcn_mfma_f32_16x16x32_bf16(a0, b1, acc01, 0, 0, 0);
            acc10 = __builtin_amdgcn_mfma_f32_16x16x32_bf16(a1, b0, acc10, 0, 0, 0);
            acc11 = __builtin_amdgcn_mfma_f32_16x16x32_bf16(a1, b1, acc11, 0, 0, 0);
        }
        #pragma unroll
        for (int r = 0; r < 4; r++) {
            s_m2[(rq + r) * M1S + nb + l15]           = f2bf(silu(acc00[r]));
            s_m2[(rq + r) * M1S + nb + 16 + l15]      = f2bf(silu(acc01[r]));
            s_m2[(16 + rq + r) * M1S + nb + l15]      = f2bf(silu(acc10[r]));
            s_m2[(16 + rq + r) * M1S + nb + 16 + l15] = f2bf(silu(acc11[r]));
        }
    }
    __syncthreads();

    // attention gate: att = sigmoid(m2 @ Wa^T + ba)
    {
        int e = tid & 31, part = tid >> 5;
        float p = 0.f;
        #pragma unroll
        for (int j = 0; j < 16; j++) {
            int d = part * 16 + j;
            p += bf2f(s_m2[e * M1S + d]) * Wa[d];
        }
        s_part[part * 32 + e] = p;
    }
    __syncthreads();
    if (tid < 32) {
        float s = ba[0];
        #pragma unroll
        for (int p = 0; p < 8; p++) s += s_part[p * 32 + tid];
        s_att[tid] = 1.f / (1.f + __expf(-s));
    }
    __syncthreads();

    // scatter: msum[row[e]] += m2[e] * att[e]
    {
        int e = tid >> 3, dg = tid & 7;
        int node = s_row[e];
        float a = s_att[e];
        float* base = g_msum + (size_t)node * DM;
        #pragma unroll
        for (int j = 0; j < 16; j++) {
            int d = j * 8 + dg;
            atomicAdd(base + d, bf2f(s_m2[e * M1S + d]) * a);
        }
    }
}

__global__ __launch_bounds__(256) void node_kernel(
    const float* __restrict__ h,
    const float* __restrict__ bh1,
    const float* __restrict__ bh2,
    float* __restrict__ out)                  // fp32 output!
{
    __shared__ __align__(16) __hip_bfloat16 s_hin[NPB * 256];
    __shared__ __align__(16) __hip_bfloat16 s_t[NPB * M1S];

    const int tid  = threadIdx.x;
    const int lane = tid & 63;
    const int wave = tid >> 6;
    const int n0   = blockIdx.x * NPB;

    // stage h (fp32 -> bf16) into h_in[:, 0:128]
    for (int i = tid; i < 32 * 16; i += 256) {
        int r = i >> 4, u = i & 15;
        int node = n0 + r; if (node >= NN) node = NN - 1;
        const float* hp = h + (size_t)node * DH + u * 8;
        float4 v0 = *(const float4*)(hp);
        float4 v1 = *(const float4*)(hp + 4);
        s16x8 t;
        t[0] = bfbits(v0.x); t[1] = bfbits(v0.y); t[2] = bfbits(v0.z); t[3] = bfbits(v0.w);
        t[4] = bfbits(v1.x); t[5] = bfbits(v1.y); t[6] = bfbits(v1.z); t[7] = bfbits(v1.w);
        *(s16x8*)(s_hin + r * 256 + u * 8) = t;
    }
    // stage msum (fp32 -> bf16) into h_in[:, 128:256]
    for (int i = tid; i < 32 * 32; i += 256) {
        int r = i >> 5, u = i & 31;
        int node = n0 + r; if (node >= NN) node = NN - 1;
        float4 v = *(const float4*)(g_msum + (size_t)node * DM + u * 4);
        s16x4 t;
        t[0] = bfbits(v.x); t[1] = bfbits(v.y); t[2] = bfbits(v.z); t[3] = bfbits(v.w);
        *(s16x4*)(s_hin + r * 256 + 128 + u * 4) = t;
    }
    __syncthreads();

    const int l15 = lane & 15;
    const int kq  = (lane >> 4) * 8;
    const int rq  = (lane >> 4) * 4;
    const int nb  = wave * 32;

    // layer 1: t = silu(h_in @ Wh1^T + bh1), K=256
    {
        float bias0 = bh1[nb + l15];
        float bias1 = bh1[nb + 16 + l15];
        f32x4 acc00 = {bias0, bias0, bias0, bias0};
        f32x4 acc01 = {bias1, bias1, bias1, bias1};
        f32x4 acc10 = acc00, acc11 = acc01;
        #pragma unroll
        for (int k0 = 0; k0 < 256; k0 += 32) {
            s16x8 a0 = *(const s16x8*)(s_hin + l15 * 256 + k0 + kq);
            s16x8 a1 = *(const s16x8*)(s_hin + (16 + l15) * 256 + k0 + kq);
            s16x8 b0 = *(const s16x8*)(g_Wh1b + (size_t)(nb + l15) * 256 + k0 + kq);
            s16x8 b1 = *(const s16x8*)(g_Wh1b + (size_t)(nb + 16 + l15) * 256 + k0 + kq);
            acc00 = __builtin_amdgcn_mfma_f32_16x16x32_bf16(a0, b0, acc00, 0, 0, 0);
            acc01 = __builtin_amdgcn_mfma_f32_16x16x32_bf16(a0, b1, acc01, 0, 0, 0);
            acc10 = __builtin_amdgcn_mfma_f32_16x16x32_bf16(a1, b0, acc10, 0, 0, 0);
            acc11 = __builtin_amdgcn_mfma_f32_16x16x32_bf16(a1, b1, acc11, 0, 0, 0);
        }
        #pragma unroll
        for (int r = 0; r < 4; r++) {
            s_t[(rq + r) * M1S + nb + l15]           = f2bf(silu(acc00[r]));
            s_t[(rq + r) * M1S + nb + 16 + l15]      = f2bf(silu(acc01[r]));
            s_t[(16 + rq + r) * M1S + nb + l15]      = f2bf(silu(acc10[r]));
            s_t[(16 + rq + r) * M1S + nb + 16 + l15] = f2bf(silu(acc11[r]));
        }
    }
    __syncthreads();

    // layer 2 + residual: out = h + t @ Wh2^T + bh2, K=128  (fp32 store)
    {
        float bias0 = bh2[nb + l15];
        float bias1 = bh2[nb + 16 + l15];
        f32x4 acc00 = {bias0, bias0, bias0, bias0};
        f32x4 acc01 = {bias1, bias1, bias1, bias1};
        f32x4 acc10 = acc00, acc11 = acc01;
        #pragma unroll
        for (int k0 = 0; k0 < 128; k0 += 32) {
            s16x8 a0 = *(const s16x8*)(s_t + l15 * M1S + k0 + kq);
            s16x8 a1 = *(const s16x8*)(s_t + (16 + l15) * M1S + k0 + kq);
            s16x8 b0 = *(const s16x8*)(g_Wh2b + (size_t)(nb + l15) * 128 + k0 + kq);
            s16x8 b1 = *(const s16x8*)(g_Wh2b + (size_t)(nb + 16 + l15) * 128 + k0 + kq);
            acc00 = __builtin_amdgcn_mfma_f32_16x16x32_bf16(a0, b0, acc00, 0, 0, 0);
            acc01 = __builtin_amdgcn_mfma_f32_16x16x32_bf16(a0, b1, acc01, 0, 0, 0);
            acc10 = __builtin_amdgcn_mfma_f32_16x16x32_bf16(a1, b0, acc10, 0, 0, 0);
            acc11 = __builtin_amdgcn_mfma_f32_16x16x32_bf16(a1, b1, acc11, 0, 0, 0);
        }
        #pragma unroll
        for (int r = 0; r < 4; r++) {
            int n00 = n0 + rq + r;
            int n16 = n0 + 16 + rq + r;
            int d0 = nb + l15, d1 = nb + 16 + l15;
            if (n00 < NN) {
                out[(size_t)n00 * DH + d0] = acc00[r] + h[(size_t)n00 * DH + d0];
                out[(size_t)n00 * DH + d1] = acc01[r] + h[(size_t)n00 * DH + d1];
            }
            if (n16 < NN) {
                out[(size_t)n16 * DH + d0] = acc10[r] + h[(size_t)n16 * DH + d0];
                out[(size_t)n16 * DH + d1] = acc11[r] + h[(size_t)n16 * DH + d1];
            }
        }
    }
}

extern "C" void kernel_launch(void* const* d_in, const int* in_sizes, int n_in,
                              void* d_out, int out_size, void* d_ws, size_t ws_size,
                              hipStream_t stream) {
    const float* x   = (const float*)d_in[0];
    const float* h   = (const float*)d_in[1];
    const float* ea  = (const float*)d_in[2];
    const float* We1 = (const float*)d_in[3];
    const float* be1 = (const float*)d_in[4];
    const float* We2 = (const float*)d_in[5];
    const float* be2 = (const float*)d_in[6];
    const float* Wh1 = (const float*)d_in[7];
    const float* bh1 = (const float*)d_in[8];
    const float* Wh2 = (const float*)d_in[9];
    const float* bh2 = (const float*)d_in[10];
    const float* Wa  = (const float*)d_in[11];
    const float* ba  = (const float*)d_in[12];
    const int* eidx  = (const int*)d_in[13];   // int32 planar [rows | cols]

    zero_msum<<<6250, 256, 0, stream>>>();
    prep_weights<<<144, 256, 0, stream>>>(We1, We2, Wh1, Wh2);
    edge_kernel<<<NE / EPB, 256, 0, stream>>>(x, h, ea, be1, be2, Wa, ba, eidx);
    node_kernel<<<(NN + NPB - 1) / NPB, 256, 0, stream>>>(h, bh1, bh2, (float*)d_out);
}